// Round 6
// baseline (283.026 us; speedup 1.0000x reference)
//
#include <hip/hip_runtime.h>
#include <math.h>

typedef __attribute__((ext_vector_type(8))) short bf16x8;
typedef __attribute__((ext_vector_type(4))) float f32x4;

__device__ __forceinline__ unsigned short f2bf(float f) {
    unsigned u = __float_as_uint(f);
    unsigned r = (u + 0x7FFF + ((u >> 16) & 1)) >> 16;   // RNE; inputs finite
    return (unsigned short)r;
}

// fast tanh: 1 - 2/(e^{2x}+1) via v_exp_f32 + v_rcp_f32 (validated R5/R6/R9).
__device__ __forceinline__ float fast_tanh(float x) {
    float e2 = __builtin_amdgcn_exp2f(x * 2.885390081777927f);  // 2*log2(e)
    return fmaf(-2.0f, __builtin_amdgcn_rcpf(e2 + 1.0f), 1.0f);
}

// async global->LDS, 16B per lane; LDS dest = wave-uniform base + lane*16.
__device__ __forceinline__ void gload_lds16(const unsigned short* g,
                                            unsigned short* l) {
    __builtin_amdgcn_global_load_lds(
        (const __attribute__((address_space(1))) unsigned int*)g,
        (__attribute__((address_space(3))) unsigned int*)l, 16, 0, 0);
}

// ---------------------------------------------------------------------------
// castT_tile: one 64(n) x 128(c) tile of fp32 (B,L,128) -> bf16 (B,128,L).
// ---------------------------------------------------------------------------
__device__ __forceinline__ void castT_tile(
    const float* __restrict__ src, unsigned short* __restrict__ dst,
    int b, int n0, int L)
{
    __shared__ unsigned short tt[128][72];
    const int tid = threadIdx.x;
    for (int i = tid; i < 64 * 32; i += 256) {
        int nr = i >> 5, c4 = (i & 31) * 4;
        float4 v = *(const float4*)(src + ((size_t)b * L + n0 + nr) * 128 + c4);
        tt[c4 + 0][nr] = f2bf(v.x);
        tt[c4 + 1][nr] = f2bf(v.y);
        tt[c4 + 2][nr] = f2bf(v.z);
        tt[c4 + 3][nr] = f2bf(v.w);
    }
    __syncthreads();
    const int c = tid >> 1, seg = (tid & 1) * 32;
    unsigned short* dp = dst + ((size_t)b * 128 + c) * L + n0 + seg;
    #pragma unroll
    for (int j = 0; j < 32; j += 8)
        *(bf16x8*)(dp + j) = *(const bf16x8*)&tt[c][seg + j];
}

// ---------------------------------------------------------------------------
// prep_all: ONE dispatch for all independent prep work (R6-proven).
// ---------------------------------------------------------------------------
__global__ __launch_bounds__(256) void prep_all(
    const float* __restrict__ x1, const float* __restrict__ x2,
    const float* __restrict__ x3,
    unsigned short* __restrict__ Xt1, unsigned short* __restrict__ Xt2,
    unsigned short* __restrict__ Xt3,
    unsigned short* __restrict__ U256, unsigned short* __restrict__ U128,
    unsigned short* __restrict__ U64p,
    const float* __restrict__ c0, const float* __restrict__ c1,
    const float* __restrict__ c2, const float* __restrict__ c3,
    unsigned short* __restrict__ BmT_all, float* __restrict__ bias_all)
{
    const int bid = blockIdx.x, tid = threadIdx.x;
    if (bid < 896) {
        if (bid < 512)      castT_tile(x1, Xt1, bid >> 2, (bid & 3) * 64, 256);
        else if (bid < 768) castT_tile(x2, Xt2, (bid - 512) >> 1, ((bid - 512) & 1) * 64, 128);
        else                castT_tile(x3, Xt3, bid - 768, 0, 64);
    } else if (bid < 1568) {
        int fid = (bid - 896) * 256 + tid;
        unsigned short* U; int L, lg, e;
        if (fid < 131072)      { U = U256; L = 256; lg = 8; e = fid; }
        else if (fid < 163840) { U = U128; L = 128; lg = 7; e = fid - 131072; }
        else                   { U = U64p; L = 64;  lg = 6; e = fid - 163840; }
        const int n = e & (L - 1);
        const int m = e >> lg;
        const int t = m >> 1;
        const float inv4L = 1.0f / (4.0f * (float)L);
        float val;
        if ((m & 1) == 0) {
            val = ((t == n) ? 0.25f : 0.0f) + (((t + n) & 1) ? -inv4L : inv4L);
        } else {
            int idx = (t - n) & (L - 1);
            double th = M_PI * (2.0 * idx + 1.0) / (2.0 * L);
            double ct = cos(th) / sin(th);
            val = (float)((idx & 1) ? -ct : ct) * inv4L;
        }
        U[e] = f2bf(val);
    } else {
        const int r   = bid - 1568;          // 0..255
        const int set = r >> 6;              // 0..3  (DEG1 = set+2)
        const int o   = ((r & 63) << 1) + (tid >> 7);
        const int i   = tid & 127;
        const int DEG1 = set + 2;
        const float* cc = (set == 0) ? c0 : (set == 1) ? c1 : (set == 2) ? c2 : c3;
        const float* cp = cc + ((size_t)i * 128 + o) * DEG1;
        unsigned short* Bm = BmT_all + (size_t)set * 65536;
        for (int d = 1; d < DEG1; ++d)
            Bm[(size_t)(d - 1) * 16384 + o * 128 + i] = f2bf(cp[d]);
        float s = cp[0];
        #pragma unroll
        for (int off = 32; off >= 1; off >>= 1) s += __shfl_down(s, off);
        __shared__ float red[4];
        if ((tid & 63) == 0) red[tid >> 6] = s;
        __syncthreads();
        if ((tid & 127) == 0)
            bias_all[set * 128 + o] = red[tid >> 6] + red[(tid >> 6) + 1];
    }
}

// ---------------------------------------------------------------------------
// up2_body (dec only): out = xh - sum_n U[m,n]*Xt[b,c,n]. R6-proven skeleton.
// ---------------------------------------------------------------------------
__device__ __forceinline__ void up2_body(
    const unsigned short* __restrict__ U,
    const unsigned short* __restrict__ Xt,
    const float* __restrict__ xh,
    float* __restrict__ out,
    int b, int mt, int L)
{
    const int NK = L >> 5;
    const int tid = threadIdx.x;
    __shared__ unsigned short Ab[2][2048];
    __shared__ unsigned short Bb[2][4096];

    const int ln = tid & 63, wv = tid >> 6;
    const int wm = wv & 1, wn = wv >> 1;
    const int lr = ln & 15, qd = ln >> 4;

    f32x4 acc[2][4];
    #pragma unroll
    for (int mi = 0; mi < 2; ++mi)
        #pragma unroll
        for (int nt = 0; nt < 4; ++nt)
            acc[mi][nt] = (f32x4){0.f, 0.f, 0.f, 0.f};

    const int arow = tid >> 2, acol = (tid & 3) * 8;

    auto stage = [&](int kk, int buf) {
        const unsigned short* ga = U + (size_t)(mt * 64 + arow) * L + kk * 32 + acol;
        gload_lds16(ga, (unsigned short*)Ab[buf] + (tid << 3));
        #pragma unroll
        for (int j = 0; j < 2; ++j) {
            int sidx = tid + (j << 8);
            const unsigned short* gb =
                Xt + ((size_t)b * 128 + (sidx >> 2)) * L + kk * 32 + (sidx & 3) * 8;
            gload_lds16(gb, (unsigned short*)Bb[buf] + (sidx << 3));
        }
    };

    stage(0, 0);
    for (int kk = 0; kk < NK; ++kk) {
        __syncthreads();
        if (kk + 1 < NK) stage(kk + 1, (kk + 1) & 1);
        const int buf = kk & 1;
        bf16x8 af[2], bfv[4];
        #pragma unroll
        for (int mi = 0; mi < 2; ++mi)
            af[mi] = *(const bf16x8*)&Ab[buf][(wm * 32 + mi * 16 + lr) * 32 + qd * 8];
        #pragma unroll
        for (int nt = 0; nt < 4; ++nt)
            bfv[nt] = *(const bf16x8*)&Bb[buf][(wn * 64 + nt * 16 + lr) * 32 + qd * 8];
        #pragma unroll
        for (int mi = 0; mi < 2; ++mi)
            #pragma unroll
            for (int nt = 0; nt < 4; ++nt)
                acc[mi][nt] = __builtin_amdgcn_mfma_f32_16x16x32_bf16(
                    af[mi], bfv[nt], acc[mi][nt], 0, 0, 0);
    }

    const int twoL = L << 1;
    #pragma unroll
    for (int nt = 0; nt < 4; ++nt) {
        const int col = wn * 64 + nt * 16 + lr;
        #pragma unroll
        for (int mi = 0; mi < 2; ++mi) {
            #pragma unroll
            for (int r = 0; r < 4; ++r) {
                const int row = mt * 64 + wm * 32 + mi * 16 + qd * 4 + r;
                const size_t gi = ((size_t)b * twoL + row) * 128 + col;
                out[gi] = xh[gi] - acc[mi][nt][r];
            }
        }
    }
}

// up2_dec: all three decomposition GEMMs in ONE dispatch.
__global__ __launch_bounds__(256) void up2_dec(
    const unsigned short* __restrict__ U64p, const unsigned short* __restrict__ U128,
    const unsigned short* __restrict__ U256,
    const unsigned short* __restrict__ Xt3, const unsigned short* __restrict__ Xt2,
    const unsigned short* __restrict__ Xt1,
    const float* __restrict__ x2, const float* __restrict__ x1,
    const float* __restrict__ x0,
    float* __restrict__ d2, float* __restrict__ d1, float* __restrict__ d0)
{
    const int bid = blockIdx.x;
    const unsigned short *U, *Xt; const float* xh; float* out;
    int L, lgMT, base;
    if (bid < 256)      { U = U64p; Xt = Xt3; xh = x2; out = d2; L = 64;  lgMT = 1; base = 0; }
    else if (bid < 768) { U = U128; Xt = Xt2; xh = x1; out = d1; L = 128; lgMT = 2; base = 256; }
    else                { U = U256; Xt = Xt1; xh = x0; out = d0; L = 256; lgMT = 3; base = 768; }
    const int rb = bid - base;
    up2_body(U, Xt, xh, out, rb >> lgMT, rb & ((1 << lgMT) - 1), L);
}

// ---------------------------------------------------------------------------
// mkan0: level-0 mkan only (deg1m1=1 -> T1 = u, no recurrence).
// 32x128 tile per block, 256 blocks. Emits m0 + transposed bf16 Xtm0.
// ---------------------------------------------------------------------------
__global__ __launch_bounds__(256) void mkan0(
    const float* __restrict__ x, const unsigned short* __restrict__ Bm,
    const float* __restrict__ bias, const float* __restrict__ w,
    float* __restrict__ m0, unsigned short* __restrict__ xtm0)
{
    __shared__ float Us[32][132];
    __shared__ unsigned short Bb[2][4096];
    const int bid = blockIdx.x, tid = threadIdx.x;
    const int mb = bid << 5;

    auto stageB = [&](int c4, int buf) {
        const int i0 = c4 << 5;
        #pragma unroll
        for (int j = 0; j < 2; ++j) {
            int sidx = tid + (j << 8);
            const unsigned short* gb =
                Bm + (size_t)(sidx >> 2) * 128 + i0 + ((sidx & 3) << 3);
            gload_lds16(gb, (unsigned short*)Bb[buf] + (sidx << 3));
        }
    };

    stageB(0, 0);

    for (int e = tid * 4; e < 4096; e += 1024) {
        const int row = e >> 7, i = e & 127;
        float4 v = *(const float4*)(x + ((size_t)(mb + row)) * 128 + i);
        float4 r;
        r.x = fast_tanh(fast_tanh(v.x));
        r.y = fast_tanh(fast_tanh(v.y));
        r.z = fast_tanh(fast_tanh(v.z));
        r.w = fast_tanh(fast_tanh(v.w));
        *(float4*)&Us[row][i] = r;
    }

    const int ln = tid & 63, wv = tid >> 6;
    const int wm = wv & 1, wn = wv >> 1;
    const int lr = ln & 15, qd = ln >> 4;
    const int arow = (wm << 4) + lr;

    f32x4 acc[4];
    #pragma unroll
    for (int nt = 0; nt < 4; ++nt) acc[nt] = (f32x4){0.f, 0.f, 0.f, 0.f};

    __syncthreads();

    for (int c4 = 0; c4 < 4; ++c4) {
        if (c4) __syncthreads();
        if (c4 + 1 < 4) stageB(c4 + 1, (c4 + 1) & 1);
        const float4 ua = *(const float4*)&Us[arow][(c4 << 5) + (qd << 3)];
        const float4 ub = *(const float4*)&Us[arow][(c4 << 5) + (qd << 3) + 4];
        union { unsigned int w[4]; bf16x8 v; } afu;
        asm("v_cvt_pk_bf16_f32 %0, %1, %2" : "=v"(afu.w[0]) : "v"(ua.x), "v"(ua.y));
        asm("v_cvt_pk_bf16_f32 %0, %1, %2" : "=v"(afu.w[1]) : "v"(ua.z), "v"(ua.w));
        asm("v_cvt_pk_bf16_f32 %0, %1, %2" : "=v"(afu.w[2]) : "v"(ub.x), "v"(ub.y));
        asm("v_cvt_pk_bf16_f32 %0, %1, %2" : "=v"(afu.w[3]) : "v"(ub.z), "v"(ub.w));
        const int buf = c4 & 1;
        bf16x8 bfv[4];
        #pragma unroll
        for (int nt = 0; nt < 4; ++nt)
            bfv[nt] = *(const bf16x8*)&Bb[buf][(((wn << 6) + (nt << 4) + lr) << 5) + (qd << 3)];
        #pragma unroll
        for (int nt = 0; nt < 4; ++nt)
            acc[nt] = __builtin_amdgcn_mfma_f32_16x16x32_bf16(afu.v, bfv[nt], acc[nt], 0, 0, 0);
    }

    #pragma unroll
    for (int nt = 0; nt < 4; ++nt) {
        const int col = (wn << 6) + (nt << 4) + lr;
        const float ww0 = w[col * 3 + 0], ww1 = w[col * 3 + 1], ww2 = w[col * 3 + 2];
        const float bs = bias[col];
        #pragma unroll
        for (int r = 0; r < 4; ++r) {
            const int row = (wm << 4) + (qd << 2) + r;
            const int gm = mb + row;
            const int n = gm & 63;
            const size_t gi = (size_t)gm * 128 + col;
            float xm1 = (n > 0)  ? x[gi - 128] : 0.f;
            float x0v = x[gi];
            float xp1 = (n < 63) ? x[gi + 128] : 0.f;
            float v = acc[nt][r] + bs + fmaf(ww0, xm1, fmaf(ww1, x0v, ww2 * xp1));
            m0[gi] = v;
            xtm0[(size_t)(((gm >> 6) << 7) + col) * 64 + n] = f2bf(v);
        }
    }
}

// ---------------------------------------------------------------------------
// chain_up: FUSED mkan_l + mix_l for level l in {1,2,3}:
//   m_l[b,n,col] = cheby_gemm(tanh2(x)) + bias + dwconv(x)
//               + sum_k U[n,k] * Xtm_in[b,col,k]
// One 32x128 output tile per block; one accumulator for both GEMMs
// (identical C-fragment mapping, accumulation order free). Kills the
// m_l fp32 write+read round trip between mkan and mix (~116MB total).
// Phases: NKc cheby (B=BmT staged, A=register Chebyshev recurrence) then
// NKu up (A=U staged in Ab, B=Xtm staged in Bb), double-buffered across
// the boundary. Epilogue writes m_l once + optional transposed Xtm_l.
// LDS: Us 16.9K + Ab 4K + Bb 16K = 37.3KB -> 4 blocks/CU.
// ---------------------------------------------------------------------------
__global__ __launch_bounds__(256) void chain_up(
    const float* __restrict__ x,            // (128*L,128) fp32 cheby/dw input
    const unsigned short* __restrict__ Bm,  // BmT for this set
    const float* __restrict__ bias,
    const float* __restrict__ w,
    const unsigned short* __restrict__ U,   // (L, L/2) bf16
    const unsigned short* __restrict__ Xtm_in, // (128,128,L/2) bf16
    float* __restrict__ mout,               // (128*L,128) fp32
    unsigned short* __restrict__ xtm_out,   // (128,128,L) bf16 or null
    int deg1m1, int lgL)
{
    __shared__ float Us[32][132];
    __shared__ unsigned short Ab[2][1024];
    __shared__ unsigned short Bb[2][4096];

    const int tid = threadIdx.x;
    const int mtsh = lgL - 5;
    const int b  = blockIdx.x >> mtsh;
    const int mt = blockIdx.x & ((1 << mtsh) - 1);
    const int L  = 1 << lgL;
    const int Ku = L >> 1;
    const int NKc = deg1m1 << 2;
    const int NKu = Ku >> 5;
    const int NT  = NKc + NKu;
    const int mbflat = (b << lgL) + (mt << 5);

    auto stageB_ch = [&](int p, int c4, int buf) {
        const int i0 = c4 << 5;
        #pragma unroll
        for (int j = 0; j < 2; ++j) {
            int sidx = tid + (j << 8);
            const unsigned short* gb =
                Bm + (size_t)((p << 7) + (sidx >> 2)) * 128 + i0 + ((sidx & 3) << 3);
            gload_lds16(gb, (unsigned short*)Bb[buf] + (sidx << 3));
        }
    };
    auto stage_up = [&](int kk, int buf) {
        if (tid < 128) {
            const unsigned short* ga =
                U + (size_t)((mt << 5) + (tid >> 2)) * Ku + kk * 32 + (tid & 3) * 8;
            gload_lds16(ga, (unsigned short*)Ab[buf] + (tid << 3));
        }
        #pragma unroll
        for (int j = 0; j < 2; ++j) {
            int sidx = tid + (j << 8);
            const unsigned short* gb =
                Xtm_in + ((size_t)b * 128 + (sidx >> 2)) * Ku + kk * 32 + (sidx & 3) * 8;
            gload_lds16(gb, (unsigned short*)Bb[buf] + (sidx << 3));
        }
    };

    stageB_ch(0, 0, 0);                      // flies during tanh prep

    for (int e = tid * 4; e < 4096; e += 1024) {
        const int row = e >> 7, i = e & 127;
        float4 v = *(const float4*)(x + ((size_t)(mbflat + row)) * 128 + i);
        float4 r;
        r.x = fast_tanh(fast_tanh(v.x));
        r.y = fast_tanh(fast_tanh(v.y));
        r.z = fast_tanh(fast_tanh(v.z));
        r.w = fast_tanh(fast_tanh(v.w));
        *(float4*)&Us[row][i] = r;
    }

    const int ln = tid & 63, wv = tid >> 6;
    const int wm = wv & 1, wn = wv >> 1;
    const int lr = ln & 15, qd = ln >> 4;
    const int arow = (wm << 4) + lr;

    f32x4 acc[4];
    #pragma unroll
    for (int nt = 0; nt < 4; ++nt) acc[nt] = (f32x4){0.f, 0.f, 0.f, 0.f};

    __syncthreads();                         // Us ready + stage(0) drained

    // ---- cheby phases (register recurrence, R9-proven) ----
    int s = 0;
    for (int c4 = 0; c4 < 4; ++c4) {
        const float4 ua = *(const float4*)&Us[arow][(c4 << 5) + (qd << 3)];
        const float4 ub = *(const float4*)&Us[arow][(c4 << 5) + (qd << 3) + 4];
        const float u0 = ua.x, u1 = ua.y, u2 = ua.z, u3 = ua.w;
        const float u4 = ub.x, u5 = ub.y, u6 = ub.z, u7 = ub.w;
        float tp0 = 1.f, tp1 = 1.f, tp2 = 1.f, tp3 = 1.f;
        float tp4 = 1.f, tp5 = 1.f, tp6 = 1.f, tp7 = 1.f;
        float tc0 = u0, tc1 = u1, tc2 = u2, tc3 = u3;
        float tc4 = u4, tc5 = u5, tc6 = u6, tc7 = u7;
        for (int p = 0; p < deg1m1; ++p, ++s) {
            if (s) __syncthreads();
            if (s + 1 < NKc) {
                int np = p + 1, nc4 = c4;
                if (np == deg1m1) { np = 0; ++nc4; }
                stageB_ch(np, nc4, (s + 1) & 1);
            } else if (s + 1 < NT) {
                stage_up(0, (s + 1) & 1);
            }
            union { unsigned int w[4]; bf16x8 v; } afu;
            asm("v_cvt_pk_bf16_f32 %0, %1, %2" : "=v"(afu.w[0]) : "v"(tc0), "v"(tc1));
            asm("v_cvt_pk_bf16_f32 %0, %1, %2" : "=v"(afu.w[1]) : "v"(tc2), "v"(tc3));
            asm("v_cvt_pk_bf16_f32 %0, %1, %2" : "=v"(afu.w[2]) : "v"(tc4), "v"(tc5));
            asm("v_cvt_pk_bf16_f32 %0, %1, %2" : "=v"(afu.w[3]) : "v"(tc6), "v"(tc7));
            const int buf = s & 1;
            bf16x8 bfv[4];
            #pragma unroll
            for (int nt = 0; nt < 4; ++nt)
                bfv[nt] = *(const bf16x8*)&Bb[buf][(((wn << 6) + (nt << 4) + lr) << 5) + (qd << 3)];
            #pragma unroll
            for (int nt = 0; nt < 4; ++nt)
                acc[nt] = __builtin_amdgcn_mfma_f32_16x16x32_bf16(afu.v, bfv[nt], acc[nt], 0, 0, 0);
            float tn;
            tn = fmaf(2.f * u0, tc0, -tp0); tp0 = tc0; tc0 = tn;
            tn = fmaf(2.f * u1, tc1, -tp1); tp1 = tc1; tc1 = tn;
            tn = fmaf(2.f * u2, tc2, -tp2); tp2 = tc2; tc2 = tn;
            tn = fmaf(2.f * u3, tc3, -tp3); tp3 = tc3; tc3 = tn;
            tn = fmaf(2.f * u4, tc4, -tp4); tp4 = tc4; tc4 = tn;
            tn = fmaf(2.f * u5, tc5, -tp5); tp5 = tc5; tc5 = tn;
            tn = fmaf(2.f * u6, tc6, -tp6); tp6 = tc6; tc6 = tn;
            tn = fmaf(2.f * u7, tc7, -tp7); tp7 = tc7; tc7 = tn;
        }
    }

    // ---- up phases (A = U from Ab, B = Xtm_in from Bb) ----
    for (int kk = 0; kk < NKu; ++kk, ++s) {
        __syncthreads();
        if (kk + 1 < NKu) stage_up(kk + 1, (s + 1) & 1);
        const int buf = s & 1;
        bf16x8 af = *(const bf16x8*)&Ab[buf][((wm << 4) + lr) * 32 + (qd << 3)];
        bf16x8 bfv[4];
        #pragma unroll
        for (int nt = 0; nt < 4; ++nt)
            bfv[nt] = *(const bf16x8*)&Bb[buf][(((wn << 6) + (nt << 4) + lr) << 5) + (qd << 3)];
        #pragma unroll
        for (int nt = 0; nt < 4; ++nt)
            acc[nt] = __builtin_amdgcn_mfma_f32_16x16x32_bf16(af, bfv[nt], acc[nt], 0, 0, 0);
    }

    // ---- epilogue: bias + dwconv + single write of m_l (+ Xtm_l emit) ----
    const int Lmask = L - 1;
    #pragma unroll
    for (int nt = 0; nt < 4; ++nt) {
        const int col = (wn << 6) + (nt << 4) + lr;
        const float ww0 = w[col * 3 + 0], ww1 = w[col * 3 + 1], ww2 = w[col * 3 + 2];
        const float bs = bias[col];
        #pragma unroll
        for (int r = 0; r < 4; ++r) {
            const int nloc = (mt << 5) + (wm << 4) + (qd << 2) + r;
            const int gm = (b << lgL) + nloc;
            const size_t gi = (size_t)gm * 128 + col;
            float xm1 = (nloc > 0)     ? x[gi - 128] : 0.f;
            float x0v = x[gi];
            float xp1 = (nloc < Lmask) ? x[gi + 128] : 0.f;
            float v = acc[nt][r] + bs + fmaf(ww0, xm1, fmaf(ww1, x0v, ww2 * xp1));
            mout[gi] = v;
            if (xtm_out)
                xtm_out[((size_t)b * 128 + col) * L + nloc] = f2bf(v);
        }
    }
}

// ---------------------------------------------------------------------------
extern "C" void kernel_launch(void* const* d_in, const int* in_sizes, int n_in,
                              void* d_out, int out_size, void* d_ws, size_t ws_size,
                              hipStream_t stream) {
    const float* x0 = (const float*)d_in[0];
    const float* x1 = (const float*)d_in[1];
    const float* x2 = (const float*)d_in[2];
    const float* x3 = (const float*)d_in[3];
    const float* c0 = (const float*)d_in[4];
    const float* w0 = (const float*)d_in[5];
    const float* c1 = (const float*)d_in[6];
    const float* w1 = (const float*)d_in[7];
    const float* c2 = (const float*)d_in[8];
    const float* w2 = (const float*)d_in[9];
    const float* c3 = (const float*)d_in[10];
    const float* w3 = (const float*)d_in[11];
    float* out = (float*)d_out;

    // ws: proven R6 layout (88.95MB), unchanged.
    float* d0 = (float*)d_ws;                               // 8388608 f
    float* d1 = d0 + 8388608;                               // 4194304 f
    float* d2 = d1 + 4194304;                               // 2097152 f
    unsigned short* Xt1  = (unsigned short*)(d2 + 2097152); // 4194304 us
    unsigned short* Xt2  = Xt1 + 4194304;                   // 2097152
    unsigned short* Xt3  = Xt2 + 2097152;                   // 1048576
    unsigned short* Xtm0 = Xt3 + 1048576;                   // 1048576
    unsigned short* Xtm1 = Xtm0 + 1048576;                  // 2097152
    unsigned short* Xtm2 = Xtm1 + 2097152;                  // 4194304
    unsigned short* BmT  = Xtm2 + 4194304;                  // 262144
    float* bias_all = (float*)(BmT + 262144);               // 512 f
    unsigned short* U256 = (unsigned short*)(bias_all + 512);
    unsigned short* U128 = U256 + 131072;
    unsigned short* U64p = U128 + 32768;                    // 8192

    float* m3 = out;                                        // (128,512,128)
    float* m2 = m3 + 8388608;                               // (128,256,128)
    float* m1 = m2 + 4194304;                               // (128,128,128)
    float* m0 = m1 + 2097152;                               // (128, 64,128)

    // 6 dispatches: levels 1-3 are fused mkan+mix chain kernels.
    prep_all<<<1824, 256, 0, stream>>>(x1, x2, x3, Xt1, Xt2, Xt3,
                                       U256, U128, U64p,
                                       c0, c1, c2, c3, BmT, bias_all);

    up2_dec<<<1792, 256, 0, stream>>>(U64p, U128, U256, Xt3, Xt2, Xt1,
                                      x2, x1, x0, d2, d1, d0);

    mkan0<<<256, 256, 0, stream>>>(x3, BmT, bias_all, w0, m0, Xtm0);

    chain_up<<<512, 256, 0, stream>>>(d2, BmT + 65536, bias_all + 128, w1,
                                      U64p, Xtm0, m1, Xtm1, 2, 7);
    chain_up<<<1024, 256, 0, stream>>>(d1, BmT + 131072, bias_all + 256, w2,
                                       U128, Xtm1, m2, Xtm2, 3, 8);
    chain_up<<<2048, 256, 0, stream>>>(d0, BmT + 196608, bias_all + 384, w3,
                                       U256, Xtm2, m3, nullptr, 4, 9);
}

// Round 7
// 265.213 us; speedup vs baseline: 1.0672x; 1.0672x over previous
//
#include <hip/hip_runtime.h>
#include <math.h>

typedef __attribute__((ext_vector_type(8))) short bf16x8;
typedef __attribute__((ext_vector_type(4))) float f32x4;

__device__ __forceinline__ unsigned short f2bf(float f) {
    unsigned u = __float_as_uint(f);
    unsigned r = (u + 0x7FFF + ((u >> 16) & 1)) >> 16;   // RNE; inputs finite
    return (unsigned short)r;
}

// fast tanh: 1 - 2/(e^{2x}+1) via v_exp_f32 + v_rcp_f32 (validated R5/R6/R9).
__device__ __forceinline__ float fast_tanh(float x) {
    float e2 = __builtin_amdgcn_exp2f(x * 2.885390081777927f);  // 2*log2(e)
    return fmaf(-2.0f, __builtin_amdgcn_rcpf(e2 + 1.0f), 1.0f);
}

// async global->LDS, 16B per lane; LDS dest = wave-uniform base + lane*16.
__device__ __forceinline__ void gload_lds16(const unsigned short* g,
                                            unsigned short* l) {
    __builtin_amdgcn_global_load_lds(
        (const __attribute__((address_space(1))) unsigned int*)g,
        (__attribute__((address_space(3))) unsigned int*)l, 16, 0, 0);
}

// ---------------------------------------------------------------------------
// castT_tile: one 64(n) x 128(c) tile of fp32 (B,L,128) -> bf16 (B,128,L).
// ---------------------------------------------------------------------------
__device__ __forceinline__ void castT_tile(
    const float* __restrict__ src, unsigned short* __restrict__ dst,
    int b, int n0, int L)
{
    __shared__ unsigned short tt[128][72];
    const int tid = threadIdx.x;
    for (int i = tid; i < 64 * 32; i += 256) {
        int nr = i >> 5, c4 = (i & 31) * 4;
        float4 v = *(const float4*)(src + ((size_t)b * L + n0 + nr) * 128 + c4);
        tt[c4 + 0][nr] = f2bf(v.x);
        tt[c4 + 1][nr] = f2bf(v.y);
        tt[c4 + 2][nr] = f2bf(v.z);
        tt[c4 + 3][nr] = f2bf(v.w);
    }
    __syncthreads();
    const int c = tid >> 1, seg = (tid & 1) * 32;
    unsigned short* dp = dst + ((size_t)b * 128 + c) * L + n0 + seg;
    #pragma unroll
    for (int j = 0; j < 32; j += 8)
        *(bf16x8*)(dp + j) = *(const bf16x8*)&tt[c][seg + j];
}

// ---------------------------------------------------------------------------
// prep_all: ONE dispatch for all independent prep work (R6-proven).
// ---------------------------------------------------------------------------
__global__ __launch_bounds__(256) void prep_all(
    const float* __restrict__ x1, const float* __restrict__ x2,
    const float* __restrict__ x3,
    unsigned short* __restrict__ Xt1, unsigned short* __restrict__ Xt2,
    unsigned short* __restrict__ Xt3,
    unsigned short* __restrict__ U256, unsigned short* __restrict__ U128,
    unsigned short* __restrict__ U64p,
    const float* __restrict__ c0, const float* __restrict__ c1,
    const float* __restrict__ c2, const float* __restrict__ c3,
    unsigned short* __restrict__ BmT_all, float* __restrict__ bias_all)
{
    const int bid = blockIdx.x, tid = threadIdx.x;
    if (bid < 896) {
        if (bid < 512)      castT_tile(x1, Xt1, bid >> 2, (bid & 3) * 64, 256);
        else if (bid < 768) castT_tile(x2, Xt2, (bid - 512) >> 1, ((bid - 512) & 1) * 64, 128);
        else                castT_tile(x3, Xt3, bid - 768, 0, 64);
    } else if (bid < 1568) {
        int fid = (bid - 896) * 256 + tid;
        unsigned short* U; int L, lg, e;
        if (fid < 131072)      { U = U256; L = 256; lg = 8; e = fid; }
        else if (fid < 163840) { U = U128; L = 128; lg = 7; e = fid - 131072; }
        else                   { U = U64p; L = 64;  lg = 6; e = fid - 163840; }
        const int n = e & (L - 1);
        const int m = e >> lg;
        const int t = m >> 1;
        const float inv4L = 1.0f / (4.0f * (float)L);
        float val;
        if ((m & 1) == 0) {
            val = ((t == n) ? 0.25f : 0.0f) + (((t + n) & 1) ? -inv4L : inv4L);
        } else {
            int idx = (t - n) & (L - 1);
            double th = M_PI * (2.0 * idx + 1.0) / (2.0 * L);
            double ct = cos(th) / sin(th);
            val = (float)((idx & 1) ? -ct : ct) * inv4L;
        }
        U[e] = f2bf(val);
    } else {
        const int r   = bid - 1568;          // 0..255
        const int set = r >> 6;              // 0..3  (DEG1 = set+2)
        const int o   = ((r & 63) << 1) + (tid >> 7);
        const int i   = tid & 127;
        const int DEG1 = set + 2;
        const float* cc = (set == 0) ? c0 : (set == 1) ? c1 : (set == 2) ? c2 : c3;
        const float* cp = cc + ((size_t)i * 128 + o) * DEG1;
        unsigned short* Bm = BmT_all + (size_t)set * 65536;
        for (int d = 1; d < DEG1; ++d)
            Bm[(size_t)(d - 1) * 16384 + o * 128 + i] = f2bf(cp[d]);
        float s = cp[0];
        #pragma unroll
        for (int off = 32; off >= 1; off >>= 1) s += __shfl_down(s, off);
        __shared__ float red[4];
        if ((tid & 63) == 0) red[tid >> 6] = s;
        __syncthreads();
        if ((tid & 127) == 0)
            bias_all[set * 128 + o] = red[tid >> 6] + red[(tid >> 6) + 1];
    }
}

// ---------------------------------------------------------------------------
// up2_body: out[b,m,c] = xh[b,m,c] + sign * sum_n U[m,n]*Xt[b,c,n]
// 64x128 tile, 4 waves 2x2 of 32x64, mfma 16x16x32 bf16.
// R11: TRIPLE-buffered staging with COUNTED s_waitcnt vmcnt(3) + raw
// s_barrier (m201 pattern) — loads for phase kk+2 issued at end of phase
// kk stay in flight across the next barrier; only the needed 3 loads/wave
// are drained per phase. Buffer (kk+2)%3 was last read in phase kk-1 and
// the phase-kk barrier separates that read from the overwrite issue.
// ---------------------------------------------------------------------------
__device__ __forceinline__ void up2_body(
    const unsigned short* __restrict__ U,
    const unsigned short* __restrict__ Xt,
    const float* __restrict__ xh,
    float* __restrict__ out,
    unsigned short* __restrict__ xtm,
    float sign, int b, int mt, int L)
{
    const int NK = L >> 5;
    const int tid = threadIdx.x;
    __shared__ unsigned short Ab[3][2048];
    __shared__ unsigned short Bb[3][4096];

    const int ln = tid & 63, wv = tid >> 6;
    const int wm = wv & 1, wn = wv >> 1;
    const int lr = ln & 15, qd = ln >> 4;

    f32x4 acc[2][4];
    #pragma unroll
    for (int mi = 0; mi < 2; ++mi)
        #pragma unroll
        for (int nt = 0; nt < 4; ++nt)
            acc[mi][nt] = (f32x4){0.f, 0.f, 0.f, 0.f};

    const int arow = tid >> 2, acol = (tid & 3) * 8;

    auto stage = [&](int kk, int buf) {
        const unsigned short* ga = U + (size_t)(mt * 64 + arow) * L + kk * 32 + acol;
        gload_lds16(ga, (unsigned short*)Ab[buf] + (tid << 3));
        #pragma unroll
        for (int j = 0; j < 2; ++j) {
            int sidx = tid + (j << 8);
            const unsigned short* gb =
                Xt + ((size_t)b * 128 + (sidx >> 2)) * L + kk * 32 + (sidx & 3) * 8;
            gload_lds16(gb, (unsigned short*)Bb[buf] + (sidx << 3));
        }
    };

    stage(0, 0);
    if (NK > 1) stage(1, 1);

    int buf = 0;
    for (int kk = 0; kk < NK; ++kk) {
        if (kk + 1 < NK) {
            asm volatile("s_waitcnt vmcnt(3)" ::: "memory");   // phase-kk loads done
        } else {
            asm volatile("s_waitcnt vmcnt(0)" ::: "memory");
        }
        __builtin_amdgcn_s_barrier();                          // all waves' loads done
        bf16x8 af[2], bfv[4];
        #pragma unroll
        for (int mi = 0; mi < 2; ++mi)
            af[mi] = *(const bf16x8*)&Ab[buf][(wm * 32 + mi * 16 + lr) * 32 + qd * 8];
        #pragma unroll
        for (int nt = 0; nt < 4; ++nt)
            bfv[nt] = *(const bf16x8*)&Bb[buf][(wn * 64 + nt * 16 + lr) * 32 + qd * 8];
        #pragma unroll
        for (int mi = 0; mi < 2; ++mi)
            #pragma unroll
            for (int nt = 0; nt < 4; ++nt)
                acc[mi][nt] = __builtin_amdgcn_mfma_f32_16x16x32_bf16(
                    af[mi], bfv[nt], acc[mi][nt], 0, 0, 0);
        if (kk + 2 < NK) {
            int nbuf = buf + 2; if (nbuf >= 3) nbuf -= 3;      // (kk+2)%3
            stage(kk + 2, nbuf);
        }
        if (++buf == 3) buf = 0;
    }

    const int twoL = L << 1;
    #pragma unroll
    for (int nt = 0; nt < 4; ++nt) {
        const int col = wn * 64 + nt * 16 + lr;
        #pragma unroll
        for (int mi = 0; mi < 2; ++mi) {
            #pragma unroll
            for (int r = 0; r < 4; ++r) {
                const int row = mt * 64 + wm * 32 + mi * 16 + qd * 4 + r;
                const size_t gi = ((size_t)b * twoL + row) * 128 + col;
                float v = xh[gi] + sign * acc[mi][nt][r];
                out[gi] = v;
                if (xtm)
                    xtm[((size_t)b * 128 + col) * twoL + row] = f2bf(v);
            }
        }
    }
}

// up2_dec: all three decomposition GEMMs in ONE dispatch.
__global__ __launch_bounds__(256) void up2_dec(
    const unsigned short* __restrict__ U64p, const unsigned short* __restrict__ U128,
    const unsigned short* __restrict__ U256,
    const unsigned short* __restrict__ Xt3, const unsigned short* __restrict__ Xt2,
    const unsigned short* __restrict__ Xt1,
    const float* __restrict__ x2, const float* __restrict__ x1,
    const float* __restrict__ x0,
    float* __restrict__ d2, float* __restrict__ d1, float* __restrict__ d0)
{
    const int bid = blockIdx.x;
    const unsigned short *U, *Xt; const float* xh; float* out;
    int L, lgMT, base;
    if (bid < 256)      { U = U64p; Xt = Xt3; xh = x2; out = d2; L = 64;  lgMT = 1; base = 0; }
    else if (bid < 768) { U = U128; Xt = Xt2; xh = x1; out = d1; L = 128; lgMT = 2; base = 256; }
    else                { U = U256; Xt = Xt1; xh = x0; out = d0; L = 256; lgMT = 3; base = 768; }
    const int rb = bid - base;
    up2_body(U, Xt, xh, out, nullptr, -1.f, rb >> lgMT, rb & ((1 << lgMT) - 1), L);
}

// up2_mix: one mix-chain up-add (in-place), optional Xtm emit for next level.
__global__ __launch_bounds__(256) void up2_mix(
    const unsigned short* __restrict__ U, const unsigned short* __restrict__ Xt,
    float* __restrict__ m, unsigned short* __restrict__ xtm, int L, int lgMT)
{
    up2_body(U, Xt, m, m, xtm, 1.f,
             blockIdx.x >> lgMT, blockIdx.x & ((1 << lgMT) - 1), L);
}

// ---------------------------------------------------------------------------
// mkan_all: ALL FOUR mkan levels in one dispatch (R9-proven, unchanged).
// Register-Chebyshev inner loop; LDS = Us 16.9K + Bb 16K = 33.3KB.
// ---------------------------------------------------------------------------
__global__ __launch_bounds__(256) void mkan_all(
    const float* __restrict__ xa, const float* __restrict__ xb,
    const float* __restrict__ xc, const float* __restrict__ xd,
    const unsigned short* __restrict__ BmT_all,
    const float* __restrict__ bias_all,
    const float* __restrict__ w0p, const float* __restrict__ w1p,
    const float* __restrict__ w2p, const float* __restrict__ w3p,
    float* __restrict__ m0, float* __restrict__ m1,
    float* __restrict__ m2, float* __restrict__ m3,
    unsigned short* __restrict__ xtm0)
{
    __shared__ float Us[32][132];            // +4 pad: bank-spread, 16B-aligned
    __shared__ unsigned short Bb[2][4096];

    const int bid = blockIdx.x, tid = threadIdx.x;
    const float *x, *w; float* outp; unsigned short* xtm = nullptr;
    int set, mb, Lmask;
    if (bid < 256)       { x = xa; w = w0p; outp = m0; set = 0; mb = bid << 5;          Lmask = 63;  xtm = xtm0; }
    else if (bid < 768)  { x = xb; w = w1p; outp = m1; set = 1; mb = (bid - 256) << 5;  Lmask = 127; }
    else if (bid < 1792) { x = xc; w = w2p; outp = m2; set = 2; mb = (bid - 768) << 5;  Lmask = 255; }
    else                 { x = xd; w = w3p; outp = m3; set = 3; mb = (bid - 1792) << 5; Lmask = 511; }
    const int deg1m1 = set + 1;
    const int NK = deg1m1 << 2;
    const unsigned short* Bm = BmT_all + (size_t)set * 65536;
    const float* bias = bias_all + (set << 7);

    auto stageB = [&](int p, int c4, int buf) {
        const int i0 = c4 << 5;
        #pragma unroll
        for (int j = 0; j < 2; ++j) {
            int sidx = tid + (j << 8);
            const unsigned short* gb =
                Bm + (size_t)((p << 7) + (sidx >> 2)) * 128 + i0 + ((sidx & 3) << 3);
            gload_lds16(gb, (unsigned short*)Bb[buf] + (sidx << 3));
        }
    };

    stageB(0, 0, 0);                         // flies during tanh prep

    // ---- prep: u = tanh(tanh(x)) fp32 into Us ----
    for (int e = tid * 4; e < 4096; e += 1024) {
        const int row = e >> 7, i = e & 127;
        float4 v = *(const float4*)(x + ((size_t)(mb + row)) * 128 + i);
        float4 r;
        r.x = fast_tanh(fast_tanh(v.x));
        r.y = fast_tanh(fast_tanh(v.y));
        r.z = fast_tanh(fast_tanh(v.z));
        r.w = fast_tanh(fast_tanh(v.w));
        *(float4*)&Us[row][i] = r;
    }

    const int ln = tid & 63, wv = tid >> 6;
    const int wm = wv & 1, wn = wv >> 1;
    const int lr = ln & 15, qd = ln >> 4;
    const int arow = (wm << 4) + lr;

    f32x4 acc[4];
    #pragma unroll
    for (int nt = 0; nt < 4; ++nt) acc[nt] = (f32x4){0.f, 0.f, 0.f, 0.f};

    __syncthreads();                         // Us ready + stage(0) drained

    int s = 0;
    for (int c4 = 0; c4 < 4; ++c4) {
        const float4 ua = *(const float4*)&Us[arow][(c4 << 5) + (qd << 3)];
        const float4 ub = *(const float4*)&Us[arow][(c4 << 5) + (qd << 3) + 4];
        const float u0 = ua.x, u1 = ua.y, u2 = ua.z, u3 = ua.w;
        const float u4 = ub.x, u5 = ub.y, u6 = ub.z, u7 = ub.w;
        float tp0 = 1.f, tp1 = 1.f, tp2 = 1.f, tp3 = 1.f;
        float tp4 = 1.f, tp5 = 1.f, tp6 = 1.f, tp7 = 1.f;
        float tc0 = u0, tc1 = u1, tc2 = u2, tc3 = u3;
        float tc4 = u4, tc5 = u5, tc6 = u6, tc7 = u7;
        for (int p = 0; p < deg1m1; ++p, ++s) {
            if (s) __syncthreads();
            if (s + 1 < NK) {
                int np = p + 1, nc4 = c4;
                if (np == deg1m1) { np = 0; ++nc4; }
                stageB(np, nc4, (s + 1) & 1);
            }
            union { unsigned int w[4]; bf16x8 v; } afu;
            asm("v_cvt_pk_bf16_f32 %0, %1, %2" : "=v"(afu.w[0]) : "v"(tc0), "v"(tc1));
            asm("v_cvt_pk_bf16_f32 %0, %1, %2" : "=v"(afu.w[1]) : "v"(tc2), "v"(tc3));
            asm("v_cvt_pk_bf16_f32 %0, %1, %2" : "=v"(afu.w[2]) : "v"(tc4), "v"(tc5));
            asm("v_cvt_pk_bf16_f32 %0, %1, %2" : "=v"(afu.w[3]) : "v"(tc6), "v"(tc7));
            const int buf = s & 1;
            bf16x8 bfv[4];
            #pragma unroll
            for (int nt = 0; nt < 4; ++nt)
                bfv[nt] = *(const bf16x8*)&Bb[buf][(((wn << 6) + (nt << 4) + lr) << 5) + (qd << 3)];
            #pragma unroll
            for (int nt = 0; nt < 4; ++nt)
                acc[nt] = __builtin_amdgcn_mfma_f32_16x16x32_bf16(afu.v, bfv[nt], acc[nt], 0, 0, 0);
            float tn;
            tn = fmaf(2.f * u0, tc0, -tp0); tp0 = tc0; tc0 = tn;
            tn = fmaf(2.f * u1, tc1, -tp1); tp1 = tc1; tc1 = tn;
            tn = fmaf(2.f * u2, tc2, -tp2); tp2 = tc2; tc2 = tn;
            tn = fmaf(2.f * u3, tc3, -tp3); tp3 = tc3; tc3 = tn;
            tn = fmaf(2.f * u4, tc4, -tp4); tp4 = tc4; tc4 = tn;
            tn = fmaf(2.f * u5, tc5, -tp5); tp5 = tc5; tc5 = tn;
            tn = fmaf(2.f * u6, tc6, -tp6); tp6 = tc6; tc6 = tn;
            tn = fmaf(2.f * u7, tc7, -tp7); tp7 = tc7; tc7 = tn;
        }
    }

    // epilogue: bias + depthwise conv3 (+ bf16-T copy for level 0 only)
    #pragma unroll
    for (int nt = 0; nt < 4; ++nt) {
        const int col = (wn << 6) + (nt << 4) + lr;
        const float ww0 = w[col * 3 + 0], ww1 = w[col * 3 + 1], ww2 = w[col * 3 + 2];
        const float bs = bias[col];
        #pragma unroll
        for (int r = 0; r < 4; ++r) {
            const int row = (wm << 4) + (qd << 2) + r;
            const int gm = mb + row;
            const int n = gm & Lmask;
            const size_t gi = (size_t)gm * 128 + col;
            float xm1 = (n > 0)     ? x[gi - 128] : 0.f;
            float x0v = x[gi];
            float xp1 = (n < Lmask) ? x[gi + 128] : 0.f;
            float v = acc[nt][r] + bs + fmaf(ww0, xm1, fmaf(ww1, x0v, ww2 * xp1));
            outp[gi] = v;
            if (xtm)
                xtm[(size_t)(((gm >> 6) << 7) + col) * 64 + (gm & 63)] = f2bf(v);
        }
    }
}

// ---------------------------------------------------------------------------
extern "C" void kernel_launch(void* const* d_in, const int* in_sizes, int n_in,
                              void* d_out, int out_size, void* d_ws, size_t ws_size,
                              hipStream_t stream) {
    const float* x0 = (const float*)d_in[0];
    const float* x1 = (const float*)d_in[1];
    const float* x2 = (const float*)d_in[2];
    const float* x3 = (const float*)d_in[3];
    const float* c0 = (const float*)d_in[4];
    const float* w0 = (const float*)d_in[5];
    const float* c1 = (const float*)d_in[6];
    const float* w1 = (const float*)d_in[7];
    const float* c2 = (const float*)d_in[8];
    const float* w2 = (const float*)d_in[9];
    const float* c3 = (const float*)d_in[10];
    const float* w3 = (const float*)d_in[11];
    float* out = (float*)d_out;

    // ws: proven R6/R9 layout (88.95MB), unchanged.
    float* d0 = (float*)d_ws;                               // 8388608 f
    float* d1 = d0 + 8388608;                               // 4194304 f
    float* d2 = d1 + 4194304;                               // 2097152 f
    unsigned short* Xt1  = (unsigned short*)(d2 + 2097152); // 4194304 us
    unsigned short* Xt2  = Xt1 + 4194304;                   // 2097152
    unsigned short* Xt3  = Xt2 + 2097152;                   // 1048576
    unsigned short* Xtm0 = Xt3 + 1048576;                   // 1048576
    unsigned short* Xtm1 = Xtm0 + 1048576;                  // 2097152
    unsigned short* Xtm2 = Xtm1 + 2097152;                  // 4194304
    unsigned short* BmT  = Xtm2 + 4194304;                  // 262144
    float* bias_all = (float*)(BmT + 262144);               // 512 f
    unsigned short* U256 = (unsigned short*)(bias_all + 512);
    unsigned short* U128 = U256 + 131072;
    unsigned short* U64p = U128 + 32768;                    // 8192

    float* m3 = out;                                        // (128,512,128)
    float* m2 = m3 + 8388608;                               // (128,256,128)
    float* m1 = m2 + 4194304;                               // (128,128,128)
    float* m0 = m1 + 2097152;                               // (128, 64,128)

    // 6 dispatches (R9-proven sequence)
    prep_all<<<1824, 256, 0, stream>>>(x1, x2, x3, Xt1, Xt2, Xt3,
                                       U256, U128, U64p,
                                       c0, c1, c2, c3, BmT, bias_all);

    up2_dec<<<1792, 256, 0, stream>>>(U64p, U128, U256, Xt3, Xt2, Xt1,
                                      x2, x1, x0, d2, d1, d0);

    mkan_all<<<3840, 256, 0, stream>>>(x3, d2, d1, d0, BmT, bias_all,
                                       w0, w1, w2, w3, m0, m1, m2, m3, Xtm0);

    up2_mix<<<256,  256, 0, stream>>>(U64p, Xtm0, m1, Xtm1, 64, 1);
    up2_mix<<<512,  256, 0, stream>>>(U128, Xtm1, m2, Xtm2, 128, 2);
    up2_mix<<<1024, 256, 0, stream>>>(U256, Xtm2, m3, nullptr, 256, 3);
}

// Round 9
// 262.434 us; speedup vs baseline: 1.0785x; 1.0106x over previous
//
#include <hip/hip_runtime.h>
#include <math.h>

typedef __attribute__((ext_vector_type(8))) short bf16x8;
typedef __attribute__((ext_vector_type(4))) float f32x4;

__device__ __forceinline__ unsigned short f2bf(float f) {
    unsigned u = __float_as_uint(f);
    unsigned r = (u + 0x7FFF + ((u >> 16) & 1)) >> 16;   // RNE; inputs finite
    return (unsigned short)r;
}

// fast tanh: 1 - 2/(e^{2x}+1) via v_exp_f32 + v_rcp_f32 (validated R5/R6/R9).
__device__ __forceinline__ float fast_tanh(float x) {
    float e2 = __builtin_amdgcn_exp2f(x * 2.885390081777927f);  // 2*log2(e)
    return fmaf(-2.0f, __builtin_amdgcn_rcpf(e2 + 1.0f), 1.0f);
}

// async global->LDS, 16B per lane; LDS dest = wave-uniform base + lane*16.
__device__ __forceinline__ void gload_lds16(const unsigned short* g,
                                            unsigned short* l) {
    __builtin_amdgcn_global_load_lds(
        (const __attribute__((address_space(1))) unsigned int*)g,
        (__attribute__((address_space(3))) unsigned int*)l, 16, 0, 0);
}

// ---------------------------------------------------------------------------
// castT_tile: one 64(n) x 128(c) tile of fp32 (B,L,128) -> bf16 (B,128,L).
// ---------------------------------------------------------------------------
__device__ __forceinline__ void castT_tile(
    const float* __restrict__ src, unsigned short* __restrict__ dst,
    int b, int n0, int L)
{
    __shared__ unsigned short tt[128][72];
    const int tid = threadIdx.x;
    for (int i = tid; i < 64 * 32; i += 256) {
        int nr = i >> 5, c4 = (i & 31) * 4;
        float4 v = *(const float4*)(src + ((size_t)b * L + n0 + nr) * 128 + c4);
        tt[c4 + 0][nr] = f2bf(v.x);
        tt[c4 + 1][nr] = f2bf(v.y);
        tt[c4 + 2][nr] = f2bf(v.z);
        tt[c4 + 3][nr] = f2bf(v.w);
    }
    __syncthreads();
    const int c = tid >> 1, seg = (tid & 1) * 32;
    unsigned short* dp = dst + ((size_t)b * 128 + c) * L + n0 + seg;
    #pragma unroll
    for (int j = 0; j < 32; j += 8)
        *(bf16x8*)(dp + j) = *(const bf16x8*)&tt[c][seg + j];
}

// ---------------------------------------------------------------------------
// prep_all: ONE dispatch for all independent prep work (R6-proven).
// ---------------------------------------------------------------------------
__global__ __launch_bounds__(256) void prep_all(
    const float* __restrict__ x1, const float* __restrict__ x2,
    const float* __restrict__ x3,
    unsigned short* __restrict__ Xt1, unsigned short* __restrict__ Xt2,
    unsigned short* __restrict__ Xt3,
    unsigned short* __restrict__ U256, unsigned short* __restrict__ U128,
    unsigned short* __restrict__ U64p,
    const float* __restrict__ c0, const float* __restrict__ c1,
    const float* __restrict__ c2, const float* __restrict__ c3,
    unsigned short* __restrict__ BmT_all, float* __restrict__ bias_all)
{
    const int bid = blockIdx.x, tid = threadIdx.x;
    if (bid < 896) {
        if (bid < 512)      castT_tile(x1, Xt1, bid >> 2, (bid & 3) * 64, 256);
        else if (bid < 768) castT_tile(x2, Xt2, (bid - 512) >> 1, ((bid - 512) & 1) * 64, 128);
        else                castT_tile(x3, Xt3, bid - 768, 0, 64);
    } else if (bid < 1568) {
        int fid = (bid - 896) * 256 + tid;
        unsigned short* U; int L, lg, e;
        if (fid < 131072)      { U = U256; L = 256; lg = 8; e = fid; }
        else if (fid < 163840) { U = U128; L = 128; lg = 7; e = fid - 131072; }
        else                   { U = U64p; L = 64;  lg = 6; e = fid - 163840; }
        const int n = e & (L - 1);
        const int m = e >> lg;
        const int t = m >> 1;
        const float inv4L = 1.0f / (4.0f * (float)L);
        float val;
        if ((m & 1) == 0) {
            val = ((t == n) ? 0.25f : 0.0f) + (((t + n) & 1) ? -inv4L : inv4L);
        } else {
            int idx = (t - n) & (L - 1);
            double th = M_PI * (2.0 * idx + 1.0) / (2.0 * L);
            double ct = cos(th) / sin(th);
            val = (float)((idx & 1) ? -ct : ct) * inv4L;
        }
        U[e] = f2bf(val);
    } else {
        const int r   = bid - 1568;          // 0..255
        const int set = r >> 6;              // 0..3  (DEG1 = set+2)
        const int o   = ((r & 63) << 1) + (tid >> 7);
        const int i   = tid & 127;
        const int DEG1 = set + 2;
        const float* cc = (set == 0) ? c0 : (set == 1) ? c1 : (set == 2) ? c2 : c3;
        const float* cp = cc + ((size_t)i * 128 + o) * DEG1;
        unsigned short* Bm = BmT_all + (size_t)set * 65536;
        for (int d = 1; d < DEG1; ++d)
            Bm[(size_t)(d - 1) * 16384 + o * 128 + i] = f2bf(cp[d]);
        float s = cp[0];
        #pragma unroll
        for (int off = 32; off >= 1; off >>= 1) s += __shfl_down(s, off);
        __shared__ float red[4];
        if ((tid & 63) == 0) red[tid >> 6] = s;
        __syncthreads();
        if ((tid & 127) == 0)
            bias_all[set * 128 + o] = red[tid >> 6] + red[(tid >> 6) + 1];
    }
}

// ---------------------------------------------------------------------------
// up2_body: out[b,m,c] = xh[b,m,c] + sign * sum_n U[m,n]*Xt[b,c,n]
// 64x128 tile, 4 waves 2x2 of 32x64, mfma 16x16x32 bf16.
// R11-verified: TRIPLE-buffered staging, counted s_waitcnt vmcnt(3) + raw
// s_barrier; loads for phase kk+2 stay in flight across barriers.
// ---------------------------------------------------------------------------
__device__ __forceinline__ void up2_body(
    const unsigned short* __restrict__ U,
    const unsigned short* __restrict__ Xt,
    const float* __restrict__ xh,
    float* __restrict__ out,
    unsigned short* __restrict__ xtm,
    float sign, int b, int mt, int L)
{
    const int NK = L >> 5;
    const int tid = threadIdx.x;
    __shared__ unsigned short Ab[3][2048];
    __shared__ unsigned short Bb[3][4096];

    const int ln = tid & 63, wv = tid >> 6;
    const int wm = wv & 1, wn = wv >> 1;
    const int lr = ln & 15, qd = ln >> 4;

    f32x4 acc[2][4];
    #pragma unroll
    for (int mi = 0; mi < 2; ++mi)
        #pragma unroll
        for (int nt = 0; nt < 4; ++nt)
            acc[mi][nt] = (f32x4){0.f, 0.f, 0.f, 0.f};

    const int arow = tid >> 2, acol = (tid & 3) * 8;

    auto stage = [&](int kk, int buf) {
        const unsigned short* ga = U + (size_t)(mt * 64 + arow) * L + kk * 32 + acol;
        gload_lds16(ga, (unsigned short*)Ab[buf] + (tid << 3));
        #pragma unroll
        for (int j = 0; j < 2; ++j) {
            int sidx = tid + (j << 8);
            const unsigned short* gb =
                Xt + ((size_t)b * 128 + (sidx >> 2)) * L + kk * 32 + (sidx & 3) * 8;
            gload_lds16(gb, (unsigned short*)Bb[buf] + (sidx << 3));
        }
    };

    stage(0, 0);
    if (NK > 1) stage(1, 1);

    int buf = 0;
    for (int kk = 0; kk < NK; ++kk) {
        if (kk + 1 < NK) {
            asm volatile("s_waitcnt vmcnt(3)" ::: "memory");   // phase-kk loads done
        } else {
            asm volatile("s_waitcnt vmcnt(0)" ::: "memory");
        }
        __builtin_amdgcn_s_barrier();                          // all waves' loads done
        bf16x8 af[2], bfv[4];
        #pragma unroll
        for (int mi = 0; mi < 2; ++mi)
            af[mi] = *(const bf16x8*)&Ab[buf][(wm * 32 + mi * 16 + lr) * 32 + qd * 8];
        #pragma unroll
        for (int nt = 0; nt < 4; ++nt)
            bfv[nt] = *(const bf16x8*)&Bb[buf][(wn * 64 + nt * 16 + lr) * 32 + qd * 8];
        #pragma unroll
        for (int mi = 0; mi < 2; ++mi)
            #pragma unroll
            for (int nt = 0; nt < 4; ++nt)
                acc[mi][nt] = __builtin_amdgcn_mfma_f32_16x16x32_bf16(
                    af[mi], bfv[nt], acc[mi][nt], 0, 0, 0);
        if (kk + 2 < NK) {
            int nbuf = buf + 2; if (nbuf >= 3) nbuf -= 3;      // (kk+2)%3
            stage(kk + 2, nbuf);
        }
        if (++buf == 3) buf = 0;
    }

    const int twoL = L << 1;
    #pragma unroll
    for (int nt = 0; nt < 4; ++nt) {
        const int col = wn * 64 + nt * 16 + lr;
        #pragma unroll
        for (int mi = 0; mi < 2; ++mi) {
            #pragma unroll
            for (int r = 0; r < 4; ++r) {
                const int row = mt * 64 + wm * 32 + mi * 16 + qd * 4 + r;
                const size_t gi = ((size_t)b * twoL + row) * 128 + col;
                float v = xh[gi] + sign * acc[mi][nt][r];
                out[gi] = v;
                if (xtm)
                    xtm[((size_t)b * 128 + col) * twoL + row] = f2bf(v);
            }
        }
    }
}

// up2_dec: all three decomposition GEMMs in ONE dispatch.
// R13: BIG-FIRST ordering (L=256 blocks dispatched first) to pack the tail.
__global__ __launch_bounds__(256) void up2_dec(
    const unsigned short* __restrict__ U64p, const unsigned short* __restrict__ U128,
    const unsigned short* __restrict__ U256,
    const unsigned short* __restrict__ Xt3, const unsigned short* __restrict__ Xt2,
    const unsigned short* __restrict__ Xt1,
    const float* __restrict__ x2, const float* __restrict__ x1,
    const float* __restrict__ x0,
    float* __restrict__ d2, float* __restrict__ d1, float* __restrict__ d0)
{
    const int bid = blockIdx.x;
    const unsigned short *U, *Xt; const float* xh; float* out;
    int L, lgMT, base;
    if (bid < 1024)      { U = U256; Xt = Xt1; xh = x0; out = d0; L = 256; lgMT = 3; base = 0; }
    else if (bid < 1536) { U = U128; Xt = Xt2; xh = x1; out = d1; L = 128; lgMT = 2; base = 1024; }
    else                 { U = U64p; Xt = Xt3; xh = x2; out = d2; L = 64;  lgMT = 1; base = 1536; }
    const int rb = bid - base;
    up2_body(U, Xt, xh, out, nullptr, -1.f, rb >> lgMT, rb & ((1 << lgMT) - 1), L);
}

// up2_mix: one mix-chain up-add (in-place), optional Xtm emit for next level.
__global__ __launch_bounds__(256) void up2_mix(
    const unsigned short* __restrict__ U, const unsigned short* __restrict__ Xt,
    float* __restrict__ m, unsigned short* __restrict__ xtm, int L, int lgMT)
{
    up2_body(U, Xt, m, m, xtm, 1.f,
             blockIdx.x >> lgMT, blockIdx.x & ((1 << lgMT) - 1), L);
}

// ---------------------------------------------------------------------------
// mkan_all: ALL FOUR mkan levels in one dispatch (register-Chebyshev, R9
// staging — double-buffered Bb + __syncthreads, the proven-safe form).
// R13: BIG-FIRST ordering only (set3/NK=16 first; set0 last).
// LDS = Us 16.9K + Bb 16K = 33.3KB.
// ---------------------------------------------------------------------------
__global__ __launch_bounds__(256) void mkan_all(
    const float* __restrict__ xa, const float* __restrict__ xb,
    const float* __restrict__ xc, const float* __restrict__ xd,
    const unsigned short* __restrict__ BmT_all,
    const float* __restrict__ bias_all,
    const float* __restrict__ w0p, const float* __restrict__ w1p,
    const float* __restrict__ w2p, const float* __restrict__ w3p,
    float* __restrict__ m0, float* __restrict__ m1,
    float* __restrict__ m2, float* __restrict__ m3,
    unsigned short* __restrict__ xtm0)
{
    __shared__ float Us[32][132];            // +4 pad: bank-spread, 16B-aligned
    __shared__ unsigned short Bb[2][4096];

    const int bid = blockIdx.x, tid = threadIdx.x;
    const float *x, *w; float* outp; unsigned short* xtm = nullptr;
    int set, mb, Lmask;
    if (bid < 2048)      { x = xd; w = w3p; outp = m3; set = 3; mb = bid << 5;          Lmask = 511; }
    else if (bid < 3072) { x = xc; w = w2p; outp = m2; set = 2; mb = (bid - 2048) << 5; Lmask = 255; }
    else if (bid < 3584) { x = xb; w = w1p; outp = m1; set = 1; mb = (bid - 3072) << 5; Lmask = 127; }
    else                 { x = xa; w = w0p; outp = m0; set = 0; mb = (bid - 3584) << 5; Lmask = 63;  xtm = xtm0; }
    const int deg1m1 = set + 1;
    const int NK = deg1m1 << 2;
    const unsigned short* Bm = BmT_all + (size_t)set * 65536;
    const float* bias = bias_all + (set << 7);

    auto stageB = [&](int p, int c4, int buf) {
        const int i0 = c4 << 5;
        #pragma unroll
        for (int j = 0; j < 2; ++j) {
            int sidx = tid + (j << 8);
            const unsigned short* gb =
                Bm + (size_t)((p << 7) + (sidx >> 2)) * 128 + i0 + ((sidx & 3) << 3);
            gload_lds16(gb, (unsigned short*)Bb[buf] + (sidx << 3));
        }
    };

    stageB(0, 0, 0);                         // flies during tanh prep

    // ---- prep: u = tanh(tanh(x)) fp32 into Us ----
    for (int e = tid * 4; e < 4096; e += 1024) {
        const int row = e >> 7, i = e & 127;
        float4 v = *(const float4*)(x + ((size_t)(mb + row)) * 128 + i);
        float4 r;
        r.x = fast_tanh(fast_tanh(v.x));
        r.y = fast_tanh(fast_tanh(v.y));
        r.z = fast_tanh(fast_tanh(v.z));
        r.w = fast_tanh(fast_tanh(v.w));
        *(float4*)&Us[row][i] = r;
    }

    const int ln = tid & 63, wv = tid >> 6;
    const int wm = wv & 1, wn = wv >> 1;
    const int lr = ln & 15, qd = ln >> 4;
    const int arow = (wm << 4) + lr;

    f32x4 acc[4];
    #pragma unroll
    for (int nt = 0; nt < 4; ++nt) acc[nt] = (f32x4){0.f, 0.f, 0.f, 0.f};

    __syncthreads();                         // Us ready + stage(0) drained

    int s = 0;
    for (int c4 = 0; c4 < 4; ++c4) {
        const float4 ua = *(const float4*)&Us[arow][(c4 << 5) + (qd << 3)];
        const float4 ub = *(const float4*)&Us[arow][(c4 << 5) + (qd << 3) + 4];
        const float u0 = ua.x, u1 = ua.y, u2 = ua.z, u3 = ua.w;
        const float u4 = ub.x, u5 = ub.y, u6 = ub.z, u7 = ub.w;
        float tp0 = 1.f, tp1 = 1.f, tp2 = 1.f, tp3 = 1.f;
        float tp4 = 1.f, tp5 = 1.f, tp6 = 1.f, tp7 = 1.f;
        float tc0 = u0, tc1 = u1, tc2 = u2, tc3 = u3;
        float tc4 = u4, tc5 = u5, tc6 = u6, tc7 = u7;
        for (int p = 0; p < deg1m1; ++p, ++s) {
            if (s) __syncthreads();
            if (s + 1 < NK) {
                int np = p + 1, nc4 = c4;
                if (np == deg1m1) { np = 0; ++nc4; }
                stageB(np, nc4, (s + 1) & 1);
            }
            union { unsigned int w[4]; bf16x8 v; } afu;
            asm("v_cvt_pk_bf16_f32 %0, %1, %2" : "=v"(afu.w[0]) : "v"(tc0), "v"(tc1));
            asm("v_cvt_pk_bf16_f32 %0, %1, %2" : "=v"(afu.w[1]) : "v"(tc2), "v"(tc3));
            asm("v_cvt_pk_bf16_f32 %0, %1, %2" : "=v"(afu.w[2]) : "v"(tc4), "v"(tc5));
            asm("v_cvt_pk_bf16_f32 %0, %1, %2" : "=v"(afu.w[3]) : "v"(tc6), "v"(tc7));
            const int buf = s & 1;
            bf16x8 bfv[4];
            #pragma unroll
            for (int nt = 0; nt < 4; ++nt)
                bfv[nt] = *(const bf16x8*)&Bb[buf][(((wn << 6) + (nt << 4) + lr) << 5) + (qd << 3)];
            #pragma unroll
            for (int nt = 0; nt < 4; ++nt)
                acc[nt] = __builtin_amdgcn_mfma_f32_16x16x32_bf16(afu.v, bfv[nt], acc[nt], 0, 0, 0);
            float tn;
            tn = fmaf(2.f * u0, tc0, -tp0); tp0 = tc0; tc0 = tn;
            tn = fmaf(2.f * u1, tc1, -tp1); tp1 = tc1; tc1 = tn;
            tn = fmaf(2.f * u2, tc2, -tp2); tp2 = tc2; tc2 = tn;
            tn = fmaf(2.f * u3, tc3, -tp3); tp3 = tc3; tc3 = tn;
            tn = fmaf(2.f * u4, tc4, -tp4); tp4 = tc4; tc4 = tn;
            tn = fmaf(2.f * u5, tc5, -tp5); tp5 = tc5; tc5 = tn;
            tn = fmaf(2.f * u6, tc6, -tp6); tp6 = tc6; tc6 = tn;
            tn = fmaf(2.f * u7, tc7, -tp7); tp7 = tc7; tc7 = tn;
        }
    }

    // epilogue: bias + depthwise conv3 (+ bf16-T copy for level 0 only)
    #pragma unroll
    for (int nt = 0; nt < 4; ++nt) {
        const int col = (wn << 6) + (nt << 4) + lr;
        const float ww0 = w[col * 3 + 0], ww1 = w[col * 3 + 1], ww2 = w[col * 3 + 2];
        const float bs = bias[col];
        #pragma unroll
        for (int r = 0; r < 4; ++r) {
            const int row = (wm << 4) + (qd << 2) + r;
            const int gm = mb + row;
            const int n = gm & Lmask;
            const size_t gi = (size_t)gm * 128 + col;
            float xm1 = (n > 0)     ? x[gi - 128] : 0.f;
            float x0v = x[gi];
            float xp1 = (n < Lmask) ? x[gi + 128] : 0.f;
            float v = acc[nt][r] + bs + fmaf(ww0, xm1, fmaf(ww1, x0v, ww2 * xp1));
            outp[gi] = v;
            if (xtm)
                xtm[(size_t)(((gm >> 6) << 7) + col) * 64 + (gm & 63)] = f2bf(v);
        }
    }
}

// ---------------------------------------------------------------------------
extern "C" void kernel_launch(void* const* d_in, const int* in_sizes, int n_in,
                              void* d_out, int out_size, void* d_ws, size_t ws_size,
                              hipStream_t stream) {
    const float* x0 = (const float*)d_in[0];
    const float* x1 = (const float*)d_in[1];
    const float* x2 = (const float*)d_in[2];
    const float* x3 = (const float*)d_in[3];
    const float* c0 = (const float*)d_in[4];
    const float* w0 = (const float*)d_in[5];
    const float* c1 = (const float*)d_in[6];
    const float* w1 = (const float*)d_in[7];
    const float* c2 = (const float*)d_in[8];
    const float* w2 = (const float*)d_in[9];
    const float* c3 = (const float*)d_in[10];
    const float* w3 = (const float*)d_in[11];
    float* out = (float*)d_out;

    // ws: proven R6/R9 layout (88.95MB), unchanged.
    float* d0 = (float*)d_ws;                               // 8388608 f
    float* d1 = d0 + 8388608;                               // 4194304 f
    float* d2 = d1 + 4194304;                               // 2097152 f
    unsigned short* Xt1  = (unsigned short*)(d2 + 2097152); // 4194304 us
    unsigned short* Xt2  = Xt1 + 4194304;                   // 2097152
    unsigned short* Xt3  = Xt2 + 2097152;                   // 1048576
    unsigned short* Xtm0 = Xt3 + 1048576;                   // 1048576
    unsigned short* Xtm1 = Xtm0 + 1048576;                  // 2097152
    unsigned short* Xtm2 = Xtm1 + 2097152;                  // 4194304
    unsigned short* BmT  = Xtm2 + 4194304;                  // 262144
    float* bias_all = (float*)(BmT + 262144);               // 512 f
    unsigned short* U256 = (unsigned short*)(bias_all + 512);
    unsigned short* U128 = U256 + 131072;
    unsigned short* U64p = U128 + 32768;                    // 8192

    float* m3 = out;                                        // (128,512,128)
    float* m2 = m3 + 8388608;                               // (128,256,128)
    float* m1 = m2 + 4194304;                               // (128,128,128)
    float* m0 = m1 + 2097152;                               // (128, 64,128)

    // 6 dispatches (R11-proven sequence; big-first block ordering inside)
    prep_all<<<1824, 256, 0, stream>>>(x1, x2, x3, Xt1, Xt2, Xt3,
                                       U256, U128, U64p,
                                       c0, c1, c2, c3, BmT, bias_all);

    up2_dec<<<1792, 256, 0, stream>>>(U64p, U128, U256, Xt3, Xt2, Xt1,
                                      x2, x1, x0, d2, d1, d0);

    mkan_all<<<3840, 256, 0, stream>>>(x3, d2, d1, d0, BmT, bias_all,
                                       w0, w1, w2, w3, m0, m1, m2, m3, Xtm0);

    up2_mix<<<256,  256, 0, stream>>>(U64p, Xtm0, m1, Xtm1, 64, 1);
    up2_mix<<<512,  256, 0, stream>>>(U128, Xtm1, m2, Xtm2, 128, 2);
    up2_mix<<<1024, 256, 0, stream>>>(U256, Xtm2, m3, nullptr, 256, 3);
}

// Round 11
// 260.306 us; speedup vs baseline: 1.0873x; 1.0082x over previous
//
#include <hip/hip_runtime.h>
#include <math.h>

typedef __attribute__((ext_vector_type(8))) short bf16x8;
typedef __attribute__((ext_vector_type(4))) float f32x4;

__device__ __forceinline__ unsigned short f2bf(float f) {
    unsigned u = __float_as_uint(f);
    unsigned r = (u + 0x7FFF + ((u >> 16) & 1)) >> 16;   // RNE; inputs finite
    return (unsigned short)r;
}

__device__ __forceinline__ float bf2f(unsigned short s) {
    return __uint_as_float(((unsigned)s) << 16);
}

// fast tanh: 1 - 2/(e^{2x}+1) via v_exp_f32 + v_rcp_f32 (validated R5/R6/R9).
__device__ __forceinline__ float fast_tanh(float x) {
    float e2 = __builtin_amdgcn_exp2f(x * 2.885390081777927f);  // 2*log2(e)
    return fmaf(-2.0f, __builtin_amdgcn_rcpf(e2 + 1.0f), 1.0f);
}

// async global->LDS, 16B per lane; LDS dest = wave-uniform base + lane*16.
__device__ __forceinline__ void gload_lds16(const unsigned short* g,
                                            unsigned short* l) {
    __builtin_amdgcn_global_load_lds(
        (const __attribute__((address_space(1))) unsigned int*)g,
        (__attribute__((address_space(3))) unsigned int*)l, 16, 0, 0);
}

// ---------------------------------------------------------------------------
// castT_tile: one 64(n) x 128(c) tile of fp32 (B,L,128) -> bf16 (B,128,L).
// ---------------------------------------------------------------------------
__device__ __forceinline__ void castT_tile(
    const float* __restrict__ src, unsigned short* __restrict__ dst,
    int b, int n0, int L)
{
    __shared__ unsigned short tt[128][72];
    const int tid = threadIdx.x;
    for (int i = tid; i < 64 * 32; i += 256) {
        int nr = i >> 5, c4 = (i & 31) * 4;
        float4 v = *(const float4*)(src + ((size_t)b * L + n0 + nr) * 128 + c4);
        tt[c4 + 0][nr] = f2bf(v.x);
        tt[c4 + 1][nr] = f2bf(v.y);
        tt[c4 + 2][nr] = f2bf(v.z);
        tt[c4 + 3][nr] = f2bf(v.w);
    }
    __syncthreads();
    const int c = tid >> 1, seg = (tid & 1) * 32;
    unsigned short* dp = dst + ((size_t)b * 128 + c) * L + n0 + seg;
    #pragma unroll
    for (int j = 0; j < 32; j += 8)
        *(bf16x8*)(dp + j) = *(const bf16x8*)&tt[c][seg + j];
}

// ---------------------------------------------------------------------------
// prep_all: ONE dispatch for all independent prep work (R6-proven).
// ---------------------------------------------------------------------------
__global__ __launch_bounds__(256) void prep_all(
    const float* __restrict__ x1, const float* __restrict__ x2,
    const float* __restrict__ x3,
    unsigned short* __restrict__ Xt1, unsigned short* __restrict__ Xt2,
    unsigned short* __restrict__ Xt3,
    unsigned short* __restrict__ U256, unsigned short* __restrict__ U128,
    unsigned short* __restrict__ U64p,
    const float* __restrict__ c0, const float* __restrict__ c1,
    const float* __restrict__ c2, const float* __restrict__ c3,
    unsigned short* __restrict__ BmT_all, float* __restrict__ bias_all)
{
    const int bid = blockIdx.x, tid = threadIdx.x;
    if (bid < 896) {
        if (bid < 512)      castT_tile(x1, Xt1, bid >> 2, (bid & 3) * 64, 256);
        else if (bid < 768) castT_tile(x2, Xt2, (bid - 512) >> 1, ((bid - 512) & 1) * 64, 128);
        else                castT_tile(x3, Xt3, bid - 768, 0, 64);
    } else if (bid < 1568) {
        int fid = (bid - 896) * 256 + tid;
        unsigned short* U; int L, lg, e;
        if (fid < 131072)      { U = U256; L = 256; lg = 8; e = fid; }
        else if (fid < 163840) { U = U128; L = 128; lg = 7; e = fid - 131072; }
        else                   { U = U64p; L = 64;  lg = 6; e = fid - 163840; }
        const int n = e & (L - 1);
        const int m = e >> lg;
        const int t = m >> 1;
        const float inv4L = 1.0f / (4.0f * (float)L);
        float val;
        if ((m & 1) == 0) {
            val = ((t == n) ? 0.25f : 0.0f) + (((t + n) & 1) ? -inv4L : inv4L);
        } else {
            int idx = (t - n) & (L - 1);
            double th = M_PI * (2.0 * idx + 1.0) / (2.0 * L);
            double ct = cos(th) / sin(th);
            val = (float)((idx & 1) ? -ct : ct) * inv4L;
        }
        U[e] = f2bf(val);
    } else {
        const int r   = bid - 1568;          // 0..255
        const int set = r >> 6;              // 0..3  (DEG1 = set+2)
        const int o   = ((r & 63) << 1) + (tid >> 7);
        const int i   = tid & 127;
        const int DEG1 = set + 2;
        const float* cc = (set == 0) ? c0 : (set == 1) ? c1 : (set == 2) ? c2 : c3;
        const float* cp = cc + ((size_t)i * 128 + o) * DEG1;
        unsigned short* Bm = BmT_all + (size_t)set * 65536;
        for (int d = 1; d < DEG1; ++d)
            Bm[(size_t)(d - 1) * 16384 + o * 128 + i] = f2bf(cp[d]);
        float s = cp[0];
        #pragma unroll
        for (int off = 32; off >= 1; off >>= 1) s += __shfl_down(s, off);
        __shared__ float red[4];
        if ((tid & 63) == 0) red[tid >> 6] = s;
        __syncthreads();
        if ((tid & 127) == 0)
            bias_all[set * 128 + o] = red[tid >> 6] + red[(tid >> 6) + 1];
    }
}

// ---------------------------------------------------------------------------
// up2_body: out[b,m,c] = xh[b,m,c] + sign * sum_n U[m,n]*Xt[b,c,n]
// 64x128 tile, 4 waves 2x2 of 32x64, mfma 16x16x32 bf16.
// R11-verified: TRIPLE-buffered staging, counted s_waitcnt vmcnt(3) + raw
// s_barrier; loads for phase kk+2 stay in flight across barriers.
// ---------------------------------------------------------------------------
__device__ __forceinline__ void up2_body(
    const unsigned short* __restrict__ U,
    const unsigned short* __restrict__ Xt,
    const float* __restrict__ xh,
    float* __restrict__ out,
    unsigned short* __restrict__ xtm,
    float sign, int b, int mt, int L)
{
    const int NK = L >> 5;
    const int tid = threadIdx.x;
    __shared__ unsigned short Ab[3][2048];
    __shared__ unsigned short Bb[3][4096];

    const int ln = tid & 63, wv = tid >> 6;
    const int wm = wv & 1, wn = wv >> 1;
    const int lr = ln & 15, qd = ln >> 4;

    f32x4 acc[2][4];
    #pragma unroll
    for (int mi = 0; mi < 2; ++mi)
        #pragma unroll
        for (int nt = 0; nt < 4; ++nt)
            acc[mi][nt] = (f32x4){0.f, 0.f, 0.f, 0.f};

    const int arow = tid >> 2, acol = (tid & 3) * 8;

    auto stage = [&](int kk, int buf) {
        const unsigned short* ga = U + (size_t)(mt * 64 + arow) * L + kk * 32 + acol;
        gload_lds16(ga, (unsigned short*)Ab[buf] + (tid << 3));
        #pragma unroll
        for (int j = 0; j < 2; ++j) {
            int sidx = tid + (j << 8);
            const unsigned short* gb =
                Xt + ((size_t)b * 128 + (sidx >> 2)) * L + kk * 32 + (sidx & 3) * 8;
            gload_lds16(gb, (unsigned short*)Bb[buf] + (sidx << 3));
        }
    };

    stage(0, 0);
    if (NK > 1) stage(1, 1);

    int buf = 0;
    for (int kk = 0; kk < NK; ++kk) {
        if (kk + 1 < NK) {
            asm volatile("s_waitcnt vmcnt(3)" ::: "memory");   // phase-kk loads done
        } else {
            asm volatile("s_waitcnt vmcnt(0)" ::: "memory");
        }
        __builtin_amdgcn_s_barrier();                          // all waves' loads done
        bf16x8 af[2], bfv[4];
        #pragma unroll
        for (int mi = 0; mi < 2; ++mi)
            af[mi] = *(const bf16x8*)&Ab[buf][(wm * 32 + mi * 16 + lr) * 32 + qd * 8];
        #pragma unroll
        for (int nt = 0; nt < 4; ++nt)
            bfv[nt] = *(const bf16x8*)&Bb[buf][(wn * 64 + nt * 16 + lr) * 32 + qd * 8];
        #pragma unroll
        for (int mi = 0; mi < 2; ++mi)
            #pragma unroll
            for (int nt = 0; nt < 4; ++nt)
                acc[mi][nt] = __builtin_amdgcn_mfma_f32_16x16x32_bf16(
                    af[mi], bfv[nt], acc[mi][nt], 0, 0, 0);
        if (kk + 2 < NK) {
            int nbuf = buf + 2; if (nbuf >= 3) nbuf -= 3;      // (kk+2)%3
            stage(kk + 2, nbuf);
        }
        if (++buf == 3) buf = 0;
    }

    const int twoL = L << 1;
    #pragma unroll
    for (int nt = 0; nt < 4; ++nt) {
        const int col = wn * 64 + nt * 16 + lr;
        #pragma unroll
        for (int mi = 0; mi < 2; ++mi) {
            #pragma unroll
            for (int r = 0; r < 4; ++r) {
                const int row = mt * 64 + wm * 32 + mi * 16 + qd * 4 + r;
                const size_t gi = ((size_t)b * twoL + row) * 128 + col;
                float v = xh[gi] + sign * acc[mi][nt][r];
                out[gi] = v;
                if (xtm)
                    xtm[((size_t)b * 128 + col) * twoL + row] = f2bf(v);
            }
        }
    }
}

// up2_dec: all three decomposition GEMMs in ONE dispatch.
// R13-verified: BIG-FIRST ordering (L=256 blocks dispatched first).
__global__ __launch_bounds__(256) void up2_dec(
    const unsigned short* __restrict__ U64p, const unsigned short* __restrict__ U128,
    const unsigned short* __restrict__ U256,
    const unsigned short* __restrict__ Xt3, const unsigned short* __restrict__ Xt2,
    const unsigned short* __restrict__ Xt1,
    const float* __restrict__ x2, const float* __restrict__ x1,
    const float* __restrict__ x0,
    float* __restrict__ d2, float* __restrict__ d1, float* __restrict__ d0)
{
    const int bid = blockIdx.x;
    const unsigned short *U, *Xt; const float* xh; float* out;
    int L, lgMT, base;
    if (bid < 1024)      { U = U256; Xt = Xt1; xh = x0; out = d0; L = 256; lgMT = 3; base = 0; }
    else if (bid < 1536) { U = U128; Xt = Xt2; xh = x1; out = d1; L = 128; lgMT = 2; base = 1024; }
    else                 { U = U64p; Xt = Xt3; xh = x2; out = d2; L = 64;  lgMT = 1; base = 1536; }
    const int rb = bid - base;
    up2_body(U, Xt, xh, out, nullptr, -1.f, rb >> lgMT, rb & ((1 << lgMT) - 1), L);
}

// up2_mix: one mix-chain up-add (in-place), optional Xtm emit for next level.
__global__ __launch_bounds__(256) void up2_mix(
    const unsigned short* __restrict__ U, const unsigned short* __restrict__ Xt,
    float* __restrict__ m, unsigned short* __restrict__ xtm, int L, int lgMT)
{
    up2_body(U, Xt, m, m, xtm, 1.f,
             blockIdx.x >> lgMT, blockIdx.x & ((1 << lgMT) - 1), L);
}

// ---------------------------------------------------------------------------
// mkan_all: ALL FOUR mkan levels in one dispatch (register-Chebyshev, R13
// structure verbatim). R15: Us stored as BF16 [32][136] (8.5KB, was fp32
// 16.9KB) -> LDS 24.7KB -> ~6 blocks/CU. T1 plane is bit-identical (stored
// u is already the bf16 RNE value cvt_pk produced); recurrence runs fp32
// from bf16-rounded u (output impact ~1e-4 << 0.037 threshold). Row stride
// 136 shorts = 68 dwords -> successive rows 4 banks apart; the 16B/lane
// read is 2-way bank-aliased only (free, m136).
// ---------------------------------------------------------------------------
__global__ __launch_bounds__(256) void mkan_all(
    const float* __restrict__ xa, const float* __restrict__ xb,
    const float* __restrict__ xc, const float* __restrict__ xd,
    const unsigned short* __restrict__ BmT_all,
    const float* __restrict__ bias_all,
    const float* __restrict__ w0p, const float* __restrict__ w1p,
    const float* __restrict__ w2p, const float* __restrict__ w3p,
    float* __restrict__ m0, float* __restrict__ m1,
    float* __restrict__ m2, float* __restrict__ m3,
    unsigned short* __restrict__ xtm0)
{
    __shared__ unsigned short Usb[32][136];  // bf16 u; +8 pad for bank spread
    __shared__ unsigned short Bb[2][4096];

    const int bid = blockIdx.x, tid = threadIdx.x;
    const float *x, *w; float* outp; unsigned short* xtm = nullptr;
    int set, mb, Lmask;
    if (bid < 2048)      { x = xd; w = w3p; outp = m3; set = 3; mb = bid << 5;          Lmask = 511; }
    else if (bid < 3072) { x = xc; w = w2p; outp = m2; set = 2; mb = (bid - 2048) << 5; Lmask = 255; }
    else if (bid < 3584) { x = xb; w = w1p; outp = m1; set = 1; mb = (bid - 3072) << 5; Lmask = 127; }
    else                 { x = xa; w = w0p; outp = m0; set = 0; mb = (bid - 3584) << 5; Lmask = 63;  xtm = xtm0; }
    const int deg1m1 = set + 1;
    const int NK = deg1m1 << 2;
    const unsigned short* Bm = BmT_all + (size_t)set * 65536;
    const float* bias = bias_all + (set << 7);

    auto stageB = [&](int p, int c4, int buf) {
        const int i0 = c4 << 5;
        #pragma unroll
        for (int j = 0; j < 2; ++j) {
            int sidx = tid + (j << 8);
            const unsigned short* gb =
                Bm + (size_t)((p << 7) + (sidx >> 2)) * 128 + i0 + ((sidx & 3) << 3);
            gload_lds16(gb, (unsigned short*)Bb[buf] + (sidx << 3));
        }
    };

    stageB(0, 0, 0);                         // flies during tanh prep

    // ---- prep: u = tanh(tanh(x)) -> bf16 into Usb ----
    for (int e = tid * 4; e < 4096; e += 1024) {
        const int row = e >> 7, i = e & 127;
        float4 v = *(const float4*)(x + ((size_t)(mb + row)) * 128 + i);
        ushort4 sv;
        sv.x = f2bf(fast_tanh(fast_tanh(v.x)));
        sv.y = f2bf(fast_tanh(fast_tanh(v.y)));
        sv.z = f2bf(fast_tanh(fast_tanh(v.z)));
        sv.w = f2bf(fast_tanh(fast_tanh(v.w)));
        *(ushort4*)&Usb[row][i] = sv;
    }

    const int ln = tid & 63, wv = tid >> 6;
    const int wm = wv & 1, wn = wv >> 1;
    const int lr = ln & 15, qd = ln >> 4;
    const int arow = (wm << 4) + lr;

    f32x4 acc[4];
    #pragma unroll
    for (int nt = 0; nt < 4; ++nt) acc[nt] = (f32x4){0.f, 0.f, 0.f, 0.f};

    __syncthreads();                         // Usb ready + stage(0) drained

    int s = 0;
    for (int c4 = 0; c4 < 4; ++c4) {
        const bf16x8 ubv = *(const bf16x8*)&Usb[arow][(c4 << 5) + (qd << 3)];
        const float u0 = bf2f((unsigned short)ubv[0]);
        const float u1 = bf2f((unsigned short)ubv[1]);
        const float u2 = bf2f((unsigned short)ubv[2]);
        const float u3 = bf2f((unsigned short)ubv[3]);
        const float u4 = bf2f((unsigned short)ubv[4]);
        const float u5 = bf2f((unsigned short)ubv[5]);
        const float u6 = bf2f((unsigned short)ubv[6]);
        const float u7 = bf2f((unsigned short)ubv[7]);
        float tp0 = 1.f, tp1 = 1.f, tp2 = 1.f, tp3 = 1.f;
        float tp4 = 1.f, tp5 = 1.f, tp6 = 1.f, tp7 = 1.f;
        float tc0 = u0, tc1 = u1, tc2 = u2, tc3 = u3;
        float tc4 = u4, tc5 = u5, tc6 = u6, tc7 = u7;
        for (int p = 0; p < deg1m1; ++p, ++s) {
            if (s) __syncthreads();
            if (s + 1 < NK) {
                int np = p + 1, nc4 = c4;
                if (np == deg1m1) { np = 0; ++nc4; }
                stageB(np, nc4, (s + 1) & 1);
            }
            union { unsigned int w[4]; bf16x8 v; } afu;
            asm("v_cvt_pk_bf16_f32 %0, %1, %2" : "=v"(afu.w[0]) : "v"(tc0), "v"(tc1));
            asm("v_cvt_pk_bf16_f32 %0, %1, %2" : "=v"(afu.w[1]) : "v"(tc2), "v"(tc3));
            asm("v_cvt_pk_bf16_f32 %0, %1, %2" : "=v"(afu.w[2]) : "v"(tc4), "v"(tc5));
            asm("v_cvt_pk_bf16_f32 %0, %1, %2" : "=v"(afu.w[3]) : "v"(tc6), "v"(tc7));
            const int buf = s & 1;
            bf16x8 bfv[4];
            #pragma unroll
            for (int nt = 0; nt < 4; ++nt)
                bfv[nt] = *(const bf16x8*)&Bb[buf][(((wn << 6) + (nt << 4) + lr) << 5) + (qd << 3)];
            #pragma unroll
            for (int nt = 0; nt < 4; ++nt)
                acc[nt] = __builtin_amdgcn_mfma_f32_16x16x32_bf16(afu.v, bfv[nt], acc[nt], 0, 0, 0);
            float tn;
            tn = fmaf(2.f * u0, tc0, -tp0); tp0 = tc0; tc0 = tn;
            tn = fmaf(2.f * u1, tc1, -tp1); tp1 = tc1; tc1 = tn;
            tn = fmaf(2.f * u2, tc2, -tp2); tp2 = tc2; tc2 = tn;
            tn = fmaf(2.f * u3, tc3, -tp3); tp3 = tc3; tc3 = tn;
            tn = fmaf(2.f * u4, tc4, -tp4); tp4 = tc4; tc4 = tn;
            tn = fmaf(2.f * u5, tc5, -tp5); tp5 = tc5; tc5 = tn;
            tn = fmaf(2.f * u6, tc6, -tp6); tp6 = tc6; tc6 = tn;
            tn = fmaf(2.f * u7, tc7, -tp7); tp7 = tc7; tc7 = tn;
        }
    }

    // epilogue: bias + depthwise conv3 (+ bf16-T copy for level 0 only)
    #pragma unroll
    for (int nt = 0; nt < 4; ++nt) {
        const int col = (wn << 6) + (nt << 4) + lr;
        const float ww0 = w[col * 3 + 0], ww1 = w[col * 3 + 1], ww2 = w[col * 3 + 2];
        const float bs = bias[col];
        #pragma unroll
        for (int r = 0; r < 4; ++r) {
            const int row = (wm << 4) + (qd << 2) + r;
            const int gm = mb + row;
            const int n = gm & Lmask;
            const size_t gi = (size_t)gm * 128 + col;
            float xm1 = (n > 0)     ? x[gi - 128] : 0.f;
            float x0v = x[gi];
            float xp1 = (n < Lmask) ? x[gi + 128] : 0.f;
            float v = acc[nt][r] + bs + fmaf(ww0, xm1, fmaf(ww1, x0v, ww2 * xp1));
            outp[gi] = v;
            if (xtm)
                xtm[(size_t)(((gm >> 6) << 7) + col) * 64 + (gm & 63)] = f2bf(v);
        }
    }
}

// ---------------------------------------------------------------------------
extern "C" void kernel_launch(void* const* d_in, const int* in_sizes, int n_in,
                              void* d_out, int out_size, void* d_ws, size_t ws_size,
                              hipStream_t stream) {
    const float* x0 = (const float*)d_in[0];
    const float* x1 = (const float*)d_in[1];
    const float* x2 = (const float*)d_in[2];
    const float* x3 = (const float*)d_in[3];
    const float* c0 = (const float*)d_in[4];
    const float* w0 = (const float*)d_in[5];
    const float* c1 = (const float*)d_in[6];
    const float* w1 = (const float*)d_in[7];
    const float* c2 = (const float*)d_in[8];
    const float* w2 = (const float*)d_in[9];
    const float* c3 = (const float*)d_in[10];
    const float* w3 = (const float*)d_in[11];
    float* out = (float*)d_out;

    // ws: proven R6/R9 layout (88.95MB), unchanged.
    float* d0 = (float*)d_ws;                               // 8388608 f
    float* d1 = d0 + 8388608;                               // 4194304 f
    float* d2 = d1 + 4194304;                               // 2097152 f
    unsigned short* Xt1  = (unsigned short*)(d2 + 2097152); // 4194304 us
    unsigned short* Xt2  = Xt1 + 4194304;                   // 2097152
    unsigned short* Xt3  = Xt2 + 2097152;                   // 1048576
    unsigned short* Xtm0 = Xt3 + 1048576;                   // 1048576
    unsigned short* Xtm1 = Xtm0 + 1048576;                  // 2097152
    unsigned short* Xtm2 = Xtm1 + 2097152;                  // 4194304
    unsigned short* BmT  = Xtm2 + 4194304;                  // 262144
    float* bias_all = (float*)(BmT + 262144);               // 512 f
    unsigned short* U256 = (unsigned short*)(bias_all + 512);
    unsigned short* U128 = U256 + 131072;
    unsigned short* U64p = U128 + 32768;                    // 8192

    float* m3 = out;                                        // (128,512,128)
    float* m2 = m3 + 8388608;                               // (128,256,128)
    float* m1 = m2 + 4194304;                               // (128,128,128)
    float* m0 = m1 + 2097152;                               // (128, 64,128)

    // 6 dispatches (R13-proven sequence; big-first ordering inside)
    prep_all<<<1824, 256, 0, stream>>>(x1, x2, x3, Xt1, Xt2, Xt3,
                                       U256, U128, U64p,
                                       c0, c1, c2, c3, BmT, bias_all);

    up2_dec<<<1792, 256, 0, stream>>>(U64p, U128, U256, Xt3, Xt2, Xt1,
                                      x2, x1, x0, d2, d1, d0);

    mkan_all<<<3840, 256, 0, stream>>>(x3, d2, d1, d0, BmT, bias_all,
                                       w0, w1, w2, w3, m0, m1, m2, m3, Xtm0);

    up2_mix<<<256,  256, 0, stream>>>(U64p, Xtm0, m1, Xtm1, 64, 1);
    up2_mix<<<512,  256, 0, stream>>>(U128, Xtm1, m2, Xtm2, 128, 2);
    up2_mix<<<1024, 256, 0, stream>>>(U256, Xtm2, m3, nullptr, 256, 3);
}